// Round 6
// baseline (245.899 us; speedup 1.0000x reference)
//
#include <hip/hip_runtime.h>
#include <math.h>

// ExodusNeuron: per-(b,n) sequential scan over T with spike threshold/reset.
// x: (B=32, T=2048, N=512, 1) fp32; weight: (1,1) fp32; out: (B,T,N,1) fp32.
//
// R9: 3-wave specialization {consumer, DMA producer, wide writer}.
//   A/B evidence so far: R7 (depth-1 DMA) == R8 (depth-2, width-16 DMA)
//   == 85us -> producer read pipeline is NOT the limiter. R3/R7/R8 all
//   converge 82-87us (~6400cy/tile) with VALUBusy 10%, HBM 29% -> the
//   common unchanged element is the WRITE path: 64 narrow (256B/wave)
//   stores per tile from the compute wave, nontemporal (no L2 ack), a
//   full vmcnt window (63) deep -> consumer issue rate becomes
//   write-ack-limited. Fix:
//     - consumer does ZERO global traffic: compute -> spikes to SBUF
//       (LDS). Only lgkm waits (fast). Explicit lgkmcnt(0) before its
//       barrier (cross-wave visibility; raw s_barrier doesn't drain).
//     - writer wave reads SBUF transposed (ds_read_b128: lane covers 4
//       neurons x row-group, 16B aligned) and issues 16
//       global_store_dwordx4 per tile (1KB coalesced each) instead of
//       64 scalar nt stores. NORMAL stores: complete at L2, write-back
//       aggregated. 16/tile never presses the vmcnt window.
//     - producer unchanged from R8 (width-16 global_load_lds, depth-2,
//       counted vmcnt(16), never 0 mid-loop).
//   LDS 96KB: XBUF 4x16KB + SBUF 2x16KB. All 3 waves execute the same
//   33-barrier sequence; writer drains tile 31 after the last barrier.
//
// Numerics MUST match numpy's fp32 rounding exactly (outputs are 0/1 spikes;
// a flipped spike = absmax 1.0): separate rounded mul/add (no FMA), and
// alpha = correctly-rounded float of exp(double(float(-0.05))).
// fire ? __fsub_rn(va,1.0f) : va is bitwise identical to va - spk.
// R0-R8 all passed with absmax == 0.0 — do not change the arithmetic.

constexpr int T_ = 2048;
constexpr int N_ = 512;
constexpr int TILE = 64;             // time steps per staged tile
constexpr int NTILE = T_ / TILE;     // 32 tiles
constexpr int NCH = 64;              // neurons per block (one per lane)
constexpr int NBUF = 4;              // XBUF depth (producer depth-2 + slack)

typedef const __attribute__((address_space(1))) void* gas_ptr;
typedef __attribute__((address_space(3))) void* las_ptr;

__global__ __launch_bounds__(192, 1)
void exodus_tri_kernel(const float* __restrict__ x,
                       const float* __restrict__ wptr,
                       float* __restrict__ out) {
    __shared__ float XBUF[NBUF][TILE][NCH];   // 64 KB staged input
    __shared__ float SBUF[2][TILE][NCH];      // 32 KB staged spikes

    const int blk  = blockIdx.x;             // 0..255
    const int b    = blk >> 3;               // 0..31
    const int n0   = (blk & 7) * NCH;        // 0,64,...,448
    const int wave = threadIdx.x >> 6;       // 0=consumer 1=producer 2=writer
    const int lane = threadIdx.x & 63;

    if (wave == 1) {
        // ============ producer: width-16 DMA, depth-2 (R8, verified) ======
        const int plane = lane >> 4;          // time-row within 4-row group
        const int sub   = lane & 15;          // 16B chunk within row
        const float* __restrict__ gl =
            x + (size_t)b * T_ * N_ + (size_t)plane * N_ + n0 + sub * 4;

#define ISSUE_TILE(TT)                                                        \
        {                                                                     \
            const float* __restrict__ g_ =                                    \
                gl + (size_t)(TT) * TILE * N_;                                \
            _Pragma("unroll")                                                 \
            for (int j0_ = 0; j0_ < TILE; j0_ += 4) {                         \
                __builtin_amdgcn_global_load_lds(                             \
                    (gas_ptr)(g_ + (size_t)j0_ * N_),                         \
                    (las_ptr)&XBUF[(TT) & (NBUF - 1)][j0_][0], 16, 0, 0);     \
            }                                                                 \
        }

        ISSUE_TILE(0);
        ISSUE_TILE(1);
        __builtin_amdgcn_sched_barrier(0);
        asm volatile("s_waitcnt vmcnt(16)");   // tile 0 landed; tile 1 flies
        __builtin_amdgcn_sched_barrier(0);
        __builtin_amdgcn_s_barrier();          // barrier 0

        for (int t = 0; t < NTILE; ++t) {
            if (t + 2 < NTILE) {
                ISSUE_TILE(t + 2);
                __builtin_amdgcn_sched_barrier(0);
                asm volatile("s_waitcnt vmcnt(16)");  // confirm t+1, fly t+2
            } else {
                asm volatile("s_waitcnt vmcnt(0)");   // tail drain
            }
            __builtin_amdgcn_sched_barrier(0);
            __builtin_amdgcn_s_barrier();
        }
#undef ISSUE_TILE
    } else if (wave == 0) {
        // ============ consumer: LDS in -> compute -> LDS out ==============
        const float w = wptr[0];
        const float alpha = (float)exp((double)(-1.0f / 20.0f));
        float vsyn = 0.0f, vmem = 0.0f;

        __builtin_amdgcn_s_barrier();          // barrier 0 (tile 0 ready)

        for (int t = 0; t < NTILE; ++t) {
            const int xb = t & (NBUF - 1);
            const int sb = t & 1;
            __builtin_amdgcn_sched_barrier(0);

            float xv[TILE];
#pragma unroll
            for (int j = 0; j < TILE; ++j) xv[j] = XBUF[xb][j][lane];

#pragma unroll
            for (int j = 0; j < TILE; ++j) {
                const float i_t = __fmul_rn(xv[j], w);
                vsyn = __fadd_rn(__fmul_rn(alpha, vsyn), i_t);
                const float va = __fadd_rn(__fmul_rn(alpha, vmem), vsyn);
                const bool fire = (va >= 1.0f);
                SBUF[sb][j][lane] = fire ? 1.0f : 0.0f;
                vmem = fire ? __fsub_rn(va, 1.0f) : va;   // == va - spk
            }
            __builtin_amdgcn_sched_barrier(0);
            // cross-wave visibility: drain ds_writes before the raw barrier
            asm volatile("s_waitcnt lgkmcnt(0)");
            __builtin_amdgcn_sched_barrier(0);
            __builtin_amdgcn_s_barrier();
        }
    } else {
        // ============ writer: SBUF -> global, 16x dwordx4 per tile ========
        const int plane = lane >> 4;          // time-row within 4-row group
        const int sub   = lane & 15;          // 4-neuron chunk within row
        float* __restrict__ ow =
            out + (size_t)b * T_ * N_ + (size_t)plane * N_ + n0 + sub * 4;

        __builtin_amdgcn_s_barrier();          // barrier 0

        for (int t = 0; t < NTILE; ++t) {
            if (t >= 1) {
                const int sb = (t - 1) & 1;
                float4 v[16];
#pragma unroll
                for (int k = 0; k < 16; ++k)
                    v[k] = *(const float4*)&SBUF[sb][4 * k + plane][sub * 4];
                float* __restrict__ o = ow + (size_t)(t - 1) * TILE * N_;
#pragma unroll
                for (int k = 0; k < 16; ++k)
                    *(float4*)(o + (size_t)(4 * k) * N_) = v[k];
            }
            __builtin_amdgcn_sched_barrier(0);
            // SBUF reads must retire before consumer overwrites this half
            asm volatile("s_waitcnt lgkmcnt(0)");
            __builtin_amdgcn_sched_barrier(0);
            __builtin_amdgcn_s_barrier();
        }
        // epilogue (after final barrier; others may have exited): tile 31
        {
            const int sb = (NTILE - 1) & 1;
            float4 v[16];
#pragma unroll
            for (int k = 0; k < 16; ++k)
                v[k] = *(const float4*)&SBUF[sb][4 * k + plane][sub * 4];
            float* __restrict__ o = ow + (size_t)(NTILE - 1) * TILE * N_;
#pragma unroll
            for (int k = 0; k < 16; ++k)
                *(float4*)(o + (size_t)(4 * k) * N_) = v[k];
        }
    }
}

extern "C" void kernel_launch(void* const* d_in, const int* in_sizes, int n_in,
                              void* d_out, int out_size, void* d_ws, size_t ws_size,
                              hipStream_t stream) {
    const float* x = (const float*)d_in[0];
    const float* w = (const float*)d_in[1];
    float* out = (float*)d_out;

    dim3 grid(256);    // one block per CU; 64 sequences per block
    dim3 block(192);   // wave0=consumer, wave1=DMA producer, wave2=writer
    hipLaunchKernelGGL(exodus_tri_kernel, grid, block, 0, stream, x, w, out);
}